// Round 3
// baseline (1201.640 us; speedup 1.0000x reference)
//
#include <hip/hip_runtime.h>

#define D 80
#define NE 1024

// ws layout:
//   [0,   8)                 : double loss accumulator (memset to 0 each call)
//   [64,  64+NE*D*4)         : normalized embed table en[NE][D]
//   [+..., +...+NE*4)        : ec[NE] = ||en_j||^2 (np sequential-k order)
//
// Bit-exact fp32 replication of the numpy reference (unchanged from round 2):
//  - squares rounded before summation; ||x||^2 via numpy pairwise 8-accumulator
//  - norms & ||e||^2 sequential k-order; dot = sequential-k fp32 FMA chain
//  - dist = fl(fl(A - 2B) + C); argmin strict < keeps first index on ties
// New in round 3: 4 waves share each 64-row group (wave w scans j in
// [256w,256w+256), en address stays wave-uniform -> scalar loads), j-loop
// unrolled x2 (two independent FMA chains), launch_bounds(256,2) to stop
// the X[80] register spill seen in round 2 (VGPR_Count was 64).

__global__ __launch_bounds__(256) void vq_prep(const float* __restrict__ w,
                                               float* __restrict__ en,
                                               float* __restrict__ ec) {
    int j = blockIdx.x * blockDim.x + threadIdx.x;
    if (j >= NE) return;
    const float* wj = w + j * D;
    float s = __fmul_rn(wj[0], wj[0]);
    for (int k = 1; k < D; ++k) s = __fadd_rn(s, __fmul_rn(wj[k], wj[k]));
    float norm = __fsqrt_rn(s);
    float* ej = en + j * D;
    float c = __fmul_rn(__fdiv_rn(wj[0], norm), __fdiv_rn(wj[0], norm));
    ej[0] = __fdiv_rn(wj[0], norm);
    for (int k = 1; k < D; ++k) {
        float v = __fdiv_rn(wj[k], norm);
        ej[k] = v;
        c = __fadd_rn(c, __fmul_rn(v, v));
    }
    ec[j] = c;
}

__global__ __launch_bounds__(256, 2) void vq_main(
        const float* __restrict__ x,    // [n, D]
        const float* __restrict__ w,    // [NE, D] unnormalized
        const float* __restrict__ en,   // [NE, D] normalized
        const float* __restrict__ ec,   // [NE]
        float* __restrict__ out,        // [n, D]
        double* __restrict__ loss_acc,
        int n) {
    const int lane = threadIdx.x & 63;
    const int wv   = threadIdx.x >> 6;          // 0..3: j-range owner
    const int row0 = blockIdx.x * 64;
    const int r    = row0 + lane;

    __shared__ float sS[4][64];
    __shared__ int   sI[4][64];
    __shared__ double bsum[4];

    float best = 3.4e38f;
    int   bi   = wv * 256;

    if (r < n) {
        float X[D];
        const float4* x4 = (const float4*)(x + (size_t)r * D);
#pragma unroll
        for (int i = 0; i < D / 4; ++i) {
            float4 v = x4[i];
            X[4 * i + 0] = v.x; X[4 * i + 1] = v.y;
            X[4 * i + 2] = v.z; X[4 * i + 3] = v.w;
        }

        // A = ||x||^2 via numpy pairwise 8-accumulator pattern (n=80, no tail)
        float pr[8];
#pragma unroll
        for (int t = 0; t < 8; ++t) pr[t] = __fmul_rn(X[t], X[t]);
#pragma unroll
        for (int base = 8; base < D; base += 8) {
#pragma unroll
            for (int t = 0; t < 8; ++t)
                pr[t] = __fadd_rn(pr[t], __fmul_rn(X[base + t], X[base + t]));
        }
        float A = __fadd_rn(
            __fadd_rn(__fadd_rn(pr[0], pr[1]), __fadd_rn(pr[2], pr[3])),
            __fadd_rn(__fadd_rn(pr[4], pr[5]), __fadd_rn(pr[6], pr[7])));

        const int j0 = wv * (NE / 4);
        for (int j = j0; j < j0 + NE / 4; j += 2) {
            const float* ea = en + j * D;       // wave-uniform -> scalar loads
            const float* eb = ea + D;
            float da = 0.f, db = 0.f;           // two independent chains (ILP)
#pragma unroll
            for (int k = 0; k < D; ++k) {
                da = __builtin_fmaf(X[k], ea[k], da);
                db = __builtin_fmaf(X[k], eb[k], db);
            }
            float sa = __fadd_rn(__fsub_rn(A, __fmul_rn(2.0f, da)), ec[j]);
            float sb = __fadd_rn(__fsub_rn(A, __fmul_rn(2.0f, db)), ec[j + 1]);
            if (sa < best) { best = sa; bi = j; }
            if (sb < best) { best = sb; bi = j + 1; }
        }
    }
    sS[wv][lane] = best;
    sI[wv][lane] = bi;
    __syncthreads();
    if (wv == 0) {
        float b = sS[0][lane]; int bx = sI[0][lane];
#pragma unroll
        for (int t = 1; t < 4; ++t) {           // strict < : lower j-range wins ties
            float s2 = sS[t][lane];
            if (s2 < b) { b = s2; bx = sI[t][lane]; }
        }
        sI[0][lane] = bx;
    }
    __syncthreads();

    // cooperative epilogue: 64 rows x 20 float4, all 256 threads
    double ss = 0.0;
    for (int f = threadIdx.x; f < 64 * (D / 4); f += 256) {
        int row = f / (D / 4);
        int gr  = row0 + row;
        if (gr < n) {
            int k4  = (f % (D / 4)) * 4;
            int gbi = sI[0][row];
            float4 q  = *(const float4*)(w + gbi * D + k4);
            float4 xv = *(const float4*)(x + (size_t)gr * D + k4);
            float d0 = __fsub_rn(q.x, xv.x), d1 = __fsub_rn(q.y, xv.y);
            float d2 = __fsub_rn(q.z, xv.z), d3 = __fsub_rn(q.w, xv.w);
            float4 o;
            o.x = __fadd_rn(xv.x, d0); o.y = __fadd_rn(xv.y, d1);
            o.z = __fadd_rn(xv.z, d2); o.w = __fadd_rn(xv.w, d3);
            *(float4*)(out + (size_t)gr * D + k4) = o;
            ss += (double)__fmul_rn(d0, d0) + (double)__fmul_rn(d1, d1);
            ss += (double)__fmul_rn(d2, d2) + (double)__fmul_rn(d3, d3);
        }
    }
#pragma unroll
    for (int off = 32; off > 0; off >>= 1) ss += __shfl_down(ss, off);
    if (lane == 0) bsum[wv] = ss;
    __syncthreads();
    if (threadIdx.x == 0) {
        atomicAdd(loss_acc, bsum[0] + bsum[1] + bsum[2] + bsum[3]);
    }
}

__global__ void vq_fin_kernel(const double* __restrict__ acc,
                              float* __restrict__ out_loss,
                              double count) {
    float m = (float)(*acc / count);
    *out_loss = __fadd_rn(m, __fmul_rn(0.25f, m));
}

extern "C" void kernel_launch(void* const* d_in, const int* in_sizes, int n_in,
                              void* d_out, int out_size, void* d_ws, size_t ws_size,
                              hipStream_t stream) {
    const float* x = (const float*)d_in[0];   // cnt_emb [64,2048,80]
    const float* w = (const float*)d_in[1];   // embed_weight [1024,80]
    float* out = (float*)d_out;

    int n = in_sizes[0] / D;                  // 131072 rows

    double* acc = (double*)d_ws;
    float* en = (float*)((char*)d_ws + 64);
    float* ec = en + NE * D;

    hipMemsetAsync(d_ws, 0, 64, stream);
    vq_prep<<<(NE + 255) / 256, 256, 0, stream>>>(w, en, ec);
    vq_main<<<(n + 63) / 64, 256, 0, stream>>>(x, w, en, ec, out, acc, n);
    vq_fin_kernel<<<1, 1, 0, stream>>>(acc, out + (size_t)n * D, (double)n * D);
}

// Round 4
// 758.744 us; speedup vs baseline: 1.5837x; 1.5837x over previous
//
#include <hip/hip_runtime.h>

#define D 80
#define NE 1024

// ws layout:
//   [0,   8)                 : double loss accumulator (memset to 0 each call)
//   [64,  64+NE*D*4)         : normalized embed table en[NE][D]
//   [+..., +...+NE*4)        : ec[NE] = ||en_j||^2 (np sequential-k order)
//
// Bit-exact fp32 replication of the numpy reference (proven in round 2):
//  - squares rounded before summation; ||x||^2 via numpy pairwise 8-accumulator
//  - norms & ||e||^2 sequential k-order; dot = sequential-k fp32 FMA chain
//  - dist = fl(fl(A - 2B) + C); argmin strict < keeps first index on ties
// Round 4: block=64 (1 wave), en pointer is workgroup-uniform (pure loop
// counter -> s_load path, SGPR~112). amdgpu_waves_per_eu(2,2) makes the
// allocator TARGET 2 waves/EU (budget 256 VGPR) so X[80] stays in registers
// (rounds 2/3 showed VGPR_Count=64 + 24-41GB scratch-thrash FETCH).

__global__ __launch_bounds__(256) void vq_prep(const float* __restrict__ w,
                                               float* __restrict__ en,
                                               float* __restrict__ ec) {
    int j = blockIdx.x * blockDim.x + threadIdx.x;
    if (j >= NE) return;
    const float* wj = w + j * D;
    float s = __fmul_rn(wj[0], wj[0]);
    for (int k = 1; k < D; ++k) s = __fadd_rn(s, __fmul_rn(wj[k], wj[k]));
    float norm = __fsqrt_rn(s);
    float* ej = en + j * D;
    float c = __fmul_rn(__fdiv_rn(wj[0], norm), __fdiv_rn(wj[0], norm));
    ej[0] = __fdiv_rn(wj[0], norm);
    for (int k = 1; k < D; ++k) {
        float v = __fdiv_rn(wj[k], norm);
        ej[k] = v;
        c = __fadd_rn(c, __fmul_rn(v, v));
    }
    ec[j] = c;
}

__global__ __launch_bounds__(64)
__attribute__((amdgpu_waves_per_eu(2, 2)))
void vq_main(
        const float* __restrict__ x,    // [n, D]
        const float* __restrict__ w,    // [NE, D] unnormalized
        const float* __restrict__ en,   // [NE, D] normalized
        const float* __restrict__ ec,   // [NE]
        float* __restrict__ out,        // [n, D]
        double* __restrict__ loss_acc,
        int n) {
    const int r = blockIdx.x * 64 + threadIdx.x;
    double ss = 0.0;
    if (r < n) {
        float X[D];
        const float4* x4 = (const float4*)(x + (size_t)r * D);
#pragma unroll
        for (int i = 0; i < D / 4; ++i) {
            float4 v = x4[i];
            X[4 * i + 0] = v.x; X[4 * i + 1] = v.y;
            X[4 * i + 2] = v.z; X[4 * i + 3] = v.w;
        }

        // A = ||x||^2 via numpy pairwise 8-accumulator pattern (n=80, no tail)
        float pr[8];
#pragma unroll
        for (int t = 0; t < 8; ++t) pr[t] = __fmul_rn(X[t], X[t]);
#pragma unroll
        for (int base = 8; base < D; base += 8) {
#pragma unroll
            for (int t = 0; t < 8; ++t)
                pr[t] = __fadd_rn(pr[t], __fmul_rn(X[base + t], X[base + t]));
        }
        float A = __fadd_rn(
            __fadd_rn(__fadd_rn(pr[0], pr[1]), __fadd_rn(pr[2], pr[3])),
            __fadd_rn(__fadd_rn(pr[4], pr[5]), __fadd_rn(pr[6], pr[7])));

        float best = 3.4e38f;
        int bi = 0;
        for (int j = 0; j < NE; j += 2) {
            const float* ea = en + j * D;   // workgroup-uniform -> s_load
            const float* eb = ea + D;
            float da = 0.f, db = 0.f;       // two independent chains (ILP)
#pragma unroll
            for (int k = 0; k < D; ++k) {
                da = __builtin_fmaf(X[k], ea[k], da);
                db = __builtin_fmaf(X[k], eb[k], db);
            }
            float sa = __fadd_rn(__fsub_rn(A, __fmul_rn(2.0f, da)), ec[j]);
            float sb = __fadd_rn(__fsub_rn(A, __fmul_rn(2.0f, db)), ec[j + 1]);
            if (sa < best) { best = sa; bi = j; }
            if (sb < best) { best = sb; bi = j + 1; }  // first index on ties
        }

        // gather unnormalized row; straight-through out = fl(x + fl(q - x))
        const float* wj = w + bi * D;
        float4* o4 = (float4*)(out + (size_t)r * D);
#pragma unroll
        for (int i = 0; i < D / 4; ++i) {
            float q0 = wj[4 * i + 0], q1 = wj[4 * i + 1];
            float q2 = wj[4 * i + 2], q3 = wj[4 * i + 3];
            float d0 = __fsub_rn(q0, X[4 * i + 0]);
            float d1 = __fsub_rn(q1, X[4 * i + 1]);
            float d2 = __fsub_rn(q2, X[4 * i + 2]);
            float d3 = __fsub_rn(q3, X[4 * i + 3]);
            float4 o;
            o.x = __fadd_rn(X[4 * i + 0], d0);
            o.y = __fadd_rn(X[4 * i + 1], d1);
            o.z = __fadd_rn(X[4 * i + 2], d2);
            o.w = __fadd_rn(X[4 * i + 3], d3);
            o4[i] = o;
            ss += (double)__fmul_rn(d0, d0) + (double)__fmul_rn(d1, d1);
            ss += (double)__fmul_rn(d2, d2) + (double)__fmul_rn(d3, d3);
        }
    }

    // single-wave block: shuffle reduce, one f64 atomic per block
#pragma unroll
    for (int off = 32; off > 0; off >>= 1) ss += __shfl_down(ss, off);
    if (threadIdx.x == 0) atomicAdd(loss_acc, ss);
}

__global__ void vq_fin_kernel(const double* __restrict__ acc,
                              float* __restrict__ out_loss,
                              double count) {
    float m = (float)(*acc / count);
    *out_loss = __fadd_rn(m, __fmul_rn(0.25f, m));
}

extern "C" void kernel_launch(void* const* d_in, const int* in_sizes, int n_in,
                              void* d_out, int out_size, void* d_ws, size_t ws_size,
                              hipStream_t stream) {
    const float* x = (const float*)d_in[0];   // cnt_emb [64,2048,80]
    const float* w = (const float*)d_in[1];   // embed_weight [1024,80]
    float* out = (float*)d_out;

    int n = in_sizes[0] / D;                  // 131072 rows

    double* acc = (double*)d_ws;
    float* en = (float*)((char*)d_ws + 64);
    float* ec = en + NE * D;

    hipMemsetAsync(d_ws, 0, 64, stream);
    vq_prep<<<(NE + 255) / 256, 256, 0, stream>>>(w, en, ec);
    vq_main<<<(n + 63) / 64, 64, 0, stream>>>(x, w, en, ec, out, acc, n);
    vq_fin_kernel<<<1, 1, 0, stream>>>(acc, out + (size_t)n * D, (double)n * D);
}

// Round 5
// 264.942 us; speedup vs baseline: 4.5355x; 2.8638x over previous
//
#include <hip/hip_runtime.h>

#define D   80
#define NE  1024
#define KP  96        // K padded to 3x32 for mfma_f32_16x16x32_bf16
#define CAP 32
#define MARGIN 0.5f   // >= 2*delta; delta <= 2*||x||max*2^-7 ~ 0.21

// ws layout (bytes):
#define OFF_ACC  0            // 8B   double loss accumulator
#define OFF_EN   64           // [NE][D] f32 normalized embed (exact, ref order)
#define OFF_EC   327744       // [NE]    f32 ||en||^2 (exact, ref order)
#define OFF_ENB  331840       // [NE][KP] bf16(-2*en), zero-padded k>=80
#define OFF_BIDX 528448       // [n] int  chosen index per row
#define OFF_CNT  1052736      // [n] int  candidate count per row
#define OFF_LIST 1577024      // [n][CAP] u16 candidate j's
#define WS_NEED  9965632

typedef __attribute__((ext_vector_type(8))) short  bf16x8;
typedef __attribute__((ext_vector_type(4))) float  f32x4;

static __device__ __forceinline__ short f2bf(float f) {   // RNE float->bf16
    unsigned u = __float_as_uint(f);
    return (short)((u + 0x7fffu + ((u >> 16) & 1u)) >> 16);
}

// ---------------- prep: exact en/ec (bit-exact ref order) + bf16(-2*en) -----
__global__ __launch_bounds__(256) void vq_prep(const float* __restrict__ w,
                                               float* __restrict__ en,
                                               float* __restrict__ ec,
                                               short* __restrict__ enb) {
    int j = blockIdx.x * blockDim.x + threadIdx.x;
    if (j >= NE) return;
    const float* wj = w + j * D;
    float s = __fmul_rn(wj[0], wj[0]);
    for (int k = 1; k < D; ++k) s = __fadd_rn(s, __fmul_rn(wj[k], wj[k]));
    float norm = __fsqrt_rn(s);
    float* ej = en + j * D;
    short* bj = enb + j * KP;
    float c = 0.f;
    for (int k = 0; k < D; ++k) {
        float v = __fdiv_rn(wj[k], norm);
        ej[k] = v;
        bj[k] = f2bf(__fmul_rn(-2.0f, v));     // exact *-2 then RNE
        float sq = __fmul_rn(v, v);
        c = (k == 0) ? sq : __fadd_rn(c, sq);  // sequential k-order like np
    }
    for (int k = D; k < KP; ++k) bj[k] = 0;
    ec[j] = c;
}

// ---------------- MFMA filter: phase A (row mins) + phase B (capture) -------
__global__ __launch_bounds__(256, 2) void vq_mfma(
        const float* __restrict__ x,
        const short* __restrict__ enb,
        const float* __restrict__ ec,
        int* __restrict__ cnt,
        unsigned short* __restrict__ list,
        int n) {
    const int lane = threadIdx.x & 63;
    const int wv   = threadIdx.x >> 6;
    const int row0 = blockIdx.x * 256 + wv * 64;   // this wave: 64 rows (4 tiles)
    const int l15  = lane & 15;
    const int lg   = lane >> 4;

    // A fragments: row = l15, k = lg*8 + s*32 (+e). Rows 80..95 are zero pad.
    bf16x8 A[4][3];
#pragma unroll
    for (int rt = 0; rt < 4; ++rt) {
        const float* xr = x + (size_t)(row0 + rt * 16 + l15) * D;
#pragma unroll
        for (int s = 0; s < 3; ++s) {
            int k0 = lg * 8 + s * 32;
            bf16x8 a;
            if (k0 < D) {
                float4 f0 = *(const float4*)(xr + k0);
                float4 f1 = *(const float4*)(xr + k0 + 4);
                a[0] = f2bf(f0.x); a[1] = f2bf(f0.y);
                a[2] = f2bf(f0.z); a[3] = f2bf(f0.w);
                a[4] = f2bf(f1.x); a[5] = f2bf(f1.y);
                a[6] = f2bf(f1.z); a[7] = f2bf(f1.w);
            } else {
#pragma unroll
                for (int e = 0; e < 8; ++e) a[e] = 0;
            }
            A[rt][s] = a;
        }
    }

    // B fragment base: col = l15 (embedding j0+l15), k = lg*8 + s*32 (+e)
    const short* bbase = enb + l15 * KP + lg * 8;

    float vmin[4][4];
#pragma unroll
    for (int rt = 0; rt < 4; ++rt)
#pragma unroll
        for (int r = 0; r < 4; ++r) vmin[rt][r] = 3.4e38f;

    // ---- phase A: full scan, track per-(lane,reg) running min ----
    for (int t = 0; t < NE / 16; ++t) {
        int j0 = t * 16;
        float ecv = ec[j0 + l15];
        const short* bp = bbase + j0 * KP;
        bf16x8 B0 = *(const bf16x8*)(bp);
        bf16x8 B1 = *(const bf16x8*)(bp + 32);
        bf16x8 B2 = *(const bf16x8*)(bp + 64);
#pragma unroll
        for (int rt = 0; rt < 4; ++rt) {
            f32x4 c = {ecv, ecv, ecv, ecv};
            c = __builtin_amdgcn_mfma_f32_16x16x32_bf16(A[rt][0], B0, c, 0, 0, 0);
            c = __builtin_amdgcn_mfma_f32_16x16x32_bf16(A[rt][1], B1, c, 0, 0, 0);
            c = __builtin_amdgcn_mfma_f32_16x16x32_bf16(A[rt][2], B2, c, 0, 0, 0);
#pragma unroll
            for (int r = 0; r < 4; ++r) vmin[rt][r] = fminf(vmin[rt][r], c[r]);
        }
    }

    // reduce mins across the 16-lane group that shares each row; add margin
    float thr[4][4];
#pragma unroll
    for (int rt = 0; rt < 4; ++rt)
#pragma unroll
        for (int r = 0; r < 4; ++r) {
            float v = vmin[rt][r];
#pragma unroll
            for (int m = 1; m < 16; m <<= 1) v = fminf(v, __shfl_xor(v, m));
            thr[rt][r] = v + MARGIN;
        }

    // ---- phase B: re-scan (deterministic recompute), capture candidates ----
    for (int t = 0; t < NE / 16; ++t) {
        int j0 = t * 16;
        float ecv = ec[j0 + l15];
        const short* bp = bbase + j0 * KP;
        bf16x8 B0 = *(const bf16x8*)(bp);
        bf16x8 B1 = *(const bf16x8*)(bp + 32);
        bf16x8 B2 = *(const bf16x8*)(bp + 64);
#pragma unroll
        for (int rt = 0; rt < 4; ++rt) {
            f32x4 c = {ecv, ecv, ecv, ecv};
            c = __builtin_amdgcn_mfma_f32_16x16x32_bf16(A[rt][0], B0, c, 0, 0, 0);
            c = __builtin_amdgcn_mfma_f32_16x16x32_bf16(A[rt][1], B1, c, 0, 0, 0);
            c = __builtin_amdgcn_mfma_f32_16x16x32_bf16(A[rt][2], B2, c, 0, 0, 0);
#pragma unroll
            for (int r = 0; r < 4; ++r) {
                if (c[r] <= thr[rt][r]) {   // C layout: col=l15, row=lg*4+r
                    int row = row0 + rt * 16 + lg * 4 + r;
                    int o = atomicAdd(cnt + row, 1);
                    if (o < CAP)
                        list[(size_t)row * CAP + o] = (unsigned short)(j0 + l15);
                }
            }
        }
    }
}

// ---------------- exact pass: bit-exact ref score on candidates only --------
__global__ __launch_bounds__(256)
__attribute__((amdgpu_waves_per_eu(1, 2)))
void vq_exact(const float* __restrict__ x,
              const float* __restrict__ en,
              const float* __restrict__ ec,
              const int* __restrict__ cnt,
              const unsigned short* __restrict__ list,
              int* __restrict__ bidx, int n) {
    int row = blockIdx.x * 256 + threadIdx.x;
    if (row >= n) return;
    float X[D];
    const float4* x4 = (const float4*)(x + (size_t)row * D);
#pragma unroll
    for (int i = 0; i < D / 4; ++i) {
        float4 v = x4[i];
        X[4 * i + 0] = v.x; X[4 * i + 1] = v.y;
        X[4 * i + 2] = v.z; X[4 * i + 3] = v.w;
    }
    // A = ||x||^2, numpy pairwise 8-accumulator pattern
    float pr[8];
#pragma unroll
    for (int t = 0; t < 8; ++t) pr[t] = __fmul_rn(X[t], X[t]);
#pragma unroll
    for (int base = 8; base < D; base += 8)
#pragma unroll
        for (int t = 0; t < 8; ++t)
            pr[t] = __fadd_rn(pr[t], __fmul_rn(X[base + t], X[base + t]));
    float A = __fadd_rn(
        __fadd_rn(__fadd_rn(pr[0], pr[1]), __fadd_rn(pr[2], pr[3])),
        __fadd_rn(__fadd_rn(pr[4], pr[5]), __fadd_rn(pr[6], pr[7])));

    float best = 3.4e38f;
    int bi = -1;
    int c = cnt[row];
    if (c > 0 && c <= CAP) {
        for (int i = 0; i < c; ++i) {
            int j = list[(size_t)row * CAP + i];
            const float* ej = en + j * D;
            float d = 0.f;
#pragma unroll
            for (int k = 0; k < D; ++k) d = __builtin_fmaf(X[k], ej[k], d);
            float s = __fadd_rn(__fsub_rn(A, __fmul_rn(2.0f, d)), ec[j]);
            // unordered list: strict < plus lowest-j on exact tie == first-index rule
            if (s < best || (s == best && j < bi)) { best = s; bi = j; }
        }
    } else {  // overflow / empty (never expected): exact full scan
        for (int j = 0; j < NE; ++j) {
            const float* ej = en + j * D;
            float d = 0.f;
#pragma unroll
            for (int k = 0; k < D; ++k) d = __builtin_fmaf(X[k], ej[k], d);
            float s = __fadd_rn(__fsub_rn(A, __fmul_rn(2.0f, d)), ec[j]);
            if (s < best) { best = s; bi = j; }
        }
    }
    bidx[row] = bi;
}

// ---------------- epilogue: coalesced gather/write + loss (proven r3) -------
__global__ __launch_bounds__(256) void vq_epi(
        const float* __restrict__ x,
        const float* __restrict__ w,
        const int* __restrict__ bidx,
        float* __restrict__ out,
        double* __restrict__ loss_acc, int n) {
    const int row0 = blockIdx.x * 64;
    double ss = 0.0;
    for (int f = threadIdx.x; f < 64 * (D / 4); f += 256) {
        int row = f / (D / 4);
        int gr  = row0 + row;
        if (gr < n) {
            int k4  = (f % (D / 4)) * 4;
            int gbi = bidx[gr];
            float4 q  = *(const float4*)(w + gbi * D + k4);
            float4 xv = *(const float4*)(x + (size_t)gr * D + k4);
            float d0 = __fsub_rn(q.x, xv.x), d1 = __fsub_rn(q.y, xv.y);
            float d2 = __fsub_rn(q.z, xv.z), d3 = __fsub_rn(q.w, xv.w);
            float4 o;
            o.x = __fadd_rn(xv.x, d0); o.y = __fadd_rn(xv.y, d1);
            o.z = __fadd_rn(xv.z, d2); o.w = __fadd_rn(xv.w, d3);
            *(float4*)(out + (size_t)gr * D + k4) = o;
            ss += (double)__fmul_rn(d0, d0) + (double)__fmul_rn(d1, d1);
            ss += (double)__fmul_rn(d2, d2) + (double)__fmul_rn(d3, d3);
        }
    }
#pragma unroll
    for (int off = 32; off > 0; off >>= 1) ss += __shfl_down(ss, off);
    __shared__ double bsum[4];
    int wid = threadIdx.x >> 6;
    if ((threadIdx.x & 63) == 0) bsum[wid] = ss;
    __syncthreads();
    if (threadIdx.x == 0)
        atomicAdd(loss_acc, bsum[0] + bsum[1] + bsum[2] + bsum[3]);
}

__global__ void vq_fin_kernel(const double* __restrict__ acc,
                              float* __restrict__ out_loss,
                              double count) {
    float m = (float)(*acc / count);
    *out_loss = __fadd_rn(m, __fmul_rn(0.25f, m));
}

// ---------------- fallback (ws too small): round-2 exact path ---------------
__global__ __launch_bounds__(64)
__attribute__((amdgpu_waves_per_eu(2, 2)))
void vq_main_exact(const float* __restrict__ x, const float* __restrict__ w,
                   const float* __restrict__ en, const float* __restrict__ ec,
                   float* __restrict__ out, double* __restrict__ loss_acc, int n) {
    const int r = blockIdx.x * 64 + threadIdx.x;
    double ss = 0.0;
    if (r < n) {
        float X[D];
        const float4* x4 = (const float4*)(x + (size_t)r * D);
#pragma unroll
        for (int i = 0; i < D / 4; ++i) {
            float4 v = x4[i];
            X[4 * i + 0] = v.x; X[4 * i + 1] = v.y;
            X[4 * i + 2] = v.z; X[4 * i + 3] = v.w;
        }
        float pr[8];
#pragma unroll
        for (int t = 0; t < 8; ++t) pr[t] = __fmul_rn(X[t], X[t]);
#pragma unroll
        for (int base = 8; base < D; base += 8)
#pragma unroll
            for (int t = 0; t < 8; ++t)
                pr[t] = __fadd_rn(pr[t], __fmul_rn(X[base + t], X[base + t]));
        float A = __fadd_rn(
            __fadd_rn(__fadd_rn(pr[0], pr[1]), __fadd_rn(pr[2], pr[3])),
            __fadd_rn(__fadd_rn(pr[4], pr[5]), __fadd_rn(pr[6], pr[7])));
        float best = 3.4e38f; int bi = 0;
        for (int j = 0; j < NE; ++j) {
            const float* ej = en + j * D;
            float d = 0.f;
#pragma unroll
            for (int k = 0; k < D; ++k) d = __builtin_fmaf(X[k], ej[k], d);
            float s = __fadd_rn(__fsub_rn(A, __fmul_rn(2.0f, d)), ec[j]);
            if (s < best) { best = s; bi = j; }
        }
        const float* wj = w + bi * D;
        float4* o4 = (float4*)(out + (size_t)r * D);
#pragma unroll
        for (int i = 0; i < D / 4; ++i) {
            float q0 = wj[4*i+0], q1 = wj[4*i+1], q2 = wj[4*i+2], q3 = wj[4*i+3];
            float d0 = __fsub_rn(q0, X[4*i+0]), d1 = __fsub_rn(q1, X[4*i+1]);
            float d2 = __fsub_rn(q2, X[4*i+2]), d3 = __fsub_rn(q3, X[4*i+3]);
            float4 o;
            o.x = __fadd_rn(X[4*i+0], d0); o.y = __fadd_rn(X[4*i+1], d1);
            o.z = __fadd_rn(X[4*i+2], d2); o.w = __fadd_rn(X[4*i+3], d3);
            o4[i] = o;
            ss += (double)__fmul_rn(d0, d0) + (double)__fmul_rn(d1, d1);
            ss += (double)__fmul_rn(d2, d2) + (double)__fmul_rn(d3, d3);
        }
    }
#pragma unroll
    for (int off = 32; off > 0; off >>= 1) ss += __shfl_down(ss, off);
    if (threadIdx.x == 0) atomicAdd(loss_acc, ss);
}

extern "C" void kernel_launch(void* const* d_in, const int* in_sizes, int n_in,
                              void* d_out, int out_size, void* d_ws, size_t ws_size,
                              hipStream_t stream) {
    const float* x = (const float*)d_in[0];   // cnt_emb [64,2048,80]
    const float* w = (const float*)d_in[1];   // embed_weight [1024,80]
    float* out = (float*)d_out;
    int n = in_sizes[0] / D;                  // 131072 rows

    char* ws = (char*)d_ws;
    double* acc = (double*)(ws + OFF_ACC);
    float*  en  = (float*)(ws + OFF_EN);
    float*  ec  = (float*)(ws + OFF_EC);

    hipMemsetAsync(ws + OFF_ACC, 0, 64, stream);
    if (ws_size >= WS_NEED) {
        short* enb = (short*)(ws + OFF_ENB);
        int*   bidx = (int*)(ws + OFF_BIDX);
        int*   cnt  = (int*)(ws + OFF_CNT);
        unsigned short* list = (unsigned short*)(ws + OFF_LIST);
        hipMemsetAsync(cnt, 0, (size_t)n * 4, stream);
        vq_prep<<<(NE + 255) / 256, 256, 0, stream>>>(w, en, ec, enb);
        vq_mfma<<<n / 256, 256, 0, stream>>>(x, enb, ec, cnt, list, n);
        vq_exact<<<n / 256, 256, 0, stream>>>(x, en, ec, cnt, list, bidx, n);
        vq_epi<<<n / 64, 256, 0, stream>>>(x, w, bidx, out, acc, n);
    } else {
        short* enb_dummy = (short*)(ws + OFF_EC + 4096);  // unused path scratch
        vq_prep<<<(NE + 255) / 256, 256, 0, stream>>>(w, en, ec, enb_dummy);
        vq_main_exact<<<(n + 63) / 64, 64, 0, stream>>>(x, w, en, ec, out, acc, n);
    }
    vq_fin_kernel<<<1, 1, 0, stream>>>(acc, out + (size_t)n * D, (double)n * D);
}

// Round 6
// 238.334 us; speedup vs baseline: 5.0418x; 1.1116x over previous
//
#include <hip/hip_runtime.h>

#define D   80
#define NE  1024
#define KP  96        // K padded to 3x32 for mfma_f32_16x16x32_bf16
#define CAP 32
#define MARGIN 0.5f   // >= 2*delta; delta <= 2*||x||max*2^-7 ~ 0.21

// ws layout (bytes):
#define OFF_ACC  0            // 8B   double loss accumulator
#define OFF_EN   64           // [NE][D] f32 normalized embed (exact, ref order)
#define OFF_EC   327744       // [NE]    f32 ||en||^2 (exact, ref order)
#define OFF_ENB  331840       // [NE][KP] bf16(-2*en), zero-padded k>=80
#define OFF_BIDX 528448       // [n] int  chosen index per row
#define OFF_CNT  1052736      // [n] int  candidate count per row
#define OFF_LIST 1577024      // [n][CAP] u16 candidate j's
#define WS_NEED  9965632

typedef __attribute__((ext_vector_type(8))) short  bf16x8;
typedef __attribute__((ext_vector_type(4))) float  f32x4;

static __device__ __forceinline__ short f2bf(float f) {   // RNE float->bf16
    unsigned u = __float_as_uint(f);
    return (short)((u + 0x7fffu + ((u >> 16) & 1u)) >> 16);
}

// ---------------- prep: exact en/ec (bit-exact ref order) + bf16(-2*en) -----
__global__ __launch_bounds__(256) void vq_prep(const float* __restrict__ w,
                                               float* __restrict__ en,
                                               float* __restrict__ ec,
                                               short* __restrict__ enb) {
    int j = blockIdx.x * blockDim.x + threadIdx.x;
    if (j >= NE) return;
    const float* wj = w + j * D;
    float s = __fmul_rn(wj[0], wj[0]);
    for (int k = 1; k < D; ++k) s = __fadd_rn(s, __fmul_rn(wj[k], wj[k]));
    float norm = __fsqrt_rn(s);
    float* ej = en + j * D;
    short* bj = enb + j * KP;
    float c = 0.f;
    for (int k = 0; k < D; ++k) {
        float v = __fdiv_rn(wj[k], norm);
        ej[k] = v;
        bj[k] = f2bf(__fmul_rn(-2.0f, v));     // exact *-2 then RNE
        float sq = __fmul_rn(v, v);
        c = (k == 0) ? sq : __fadd_rn(c, sq);  // sequential k-order like np
    }
    for (int k = D; k < KP; ++k) bj[k] = 0;
    ec[j] = c;
}

// ---------------- MFMA filter: phase A (row mins) + phase B (capture) -------
// amdgpu_waves_per_eu(2,2): round-5 showed launch_bounds(256,2) still let the
// allocator target 64 VGPR and spill the 48-VGPR A-fragment set into the
// inner loop (MfmaUtil 11.7% vs 25us pipe floor). Budget 256 VGPR -> resident.
__global__ __launch_bounds__(256)
__attribute__((amdgpu_waves_per_eu(2, 2)))
void vq_mfma(
        const float* __restrict__ x,
        const short* __restrict__ enb,
        const float* __restrict__ ec,
        int* __restrict__ cnt,
        unsigned short* __restrict__ list,
        int n) {
    const int lane = threadIdx.x & 63;
    const int wv   = threadIdx.x >> 6;
    const int row0 = blockIdx.x * 256 + wv * 64;   // this wave: 64 rows (4 tiles)
    const int l15  = lane & 15;
    const int lg   = lane >> 4;

    // A fragments: row = l15, k = lg*8 + s*32 (+e). k>=80 is zero pad.
    bf16x8 A[4][3];
#pragma unroll
    for (int rt = 0; rt < 4; ++rt) {
        const float* xr = x + (size_t)(row0 + rt * 16 + l15) * D;
#pragma unroll
        for (int s = 0; s < 3; ++s) {
            int k0 = lg * 8 + s * 32;
            bf16x8 a;
            if (k0 < D) {
                float4 f0 = *(const float4*)(xr + k0);
                float4 f1 = *(const float4*)(xr + k0 + 4);
                a[0] = f2bf(f0.x); a[1] = f2bf(f0.y);
                a[2] = f2bf(f0.z); a[3] = f2bf(f0.w);
                a[4] = f2bf(f1.x); a[5] = f2bf(f1.y);
                a[6] = f2bf(f1.z); a[7] = f2bf(f1.w);
            } else {
#pragma unroll
                for (int e = 0; e < 8; ++e) a[e] = 0;
            }
            A[rt][s] = a;
        }
    }

    // B fragment base: col = l15 (embedding j0+l15), k = lg*8 + s*32 (+e)
    const short* bbase = enb + l15 * KP + lg * 8;

    float vmin[4][4];
#pragma unroll
    for (int rt = 0; rt < 4; ++rt)
#pragma unroll
        for (int r = 0; r < 4; ++r) vmin[rt][r] = 3.4e38f;

    // ---- phase A: full scan, track per-(lane,reg) running min ----
    {
        bf16x8 B0 = *(const bf16x8*)(bbase);
        bf16x8 B1 = *(const bf16x8*)(bbase + 32);
        bf16x8 B2 = *(const bf16x8*)(bbase + 64);
        float ecv = ec[l15];
        for (int t = 0; t < NE / 16; ++t) {
            bf16x8 N0 = B0, N1 = B1, N2 = B2;   // prefetch next tile (dbuf)
            float ecn = ecv;
            if (t + 1 < NE / 16) {
                const short* np = bbase + (t + 1) * 16 * KP;
                N0 = *(const bf16x8*)(np);
                N1 = *(const bf16x8*)(np + 32);
                N2 = *(const bf16x8*)(np + 64);
                ecn = ec[(t + 1) * 16 + l15];
            }
#pragma unroll
            for (int rt = 0; rt < 4; ++rt) {
                f32x4 c = {ecv, ecv, ecv, ecv};
                c = __builtin_amdgcn_mfma_f32_16x16x32_bf16(A[rt][0], B0, c, 0, 0, 0);
                c = __builtin_amdgcn_mfma_f32_16x16x32_bf16(A[rt][1], B1, c, 0, 0, 0);
                c = __builtin_amdgcn_mfma_f32_16x16x32_bf16(A[rt][2], B2, c, 0, 0, 0);
#pragma unroll
                for (int r = 0; r < 4; ++r) vmin[rt][r] = fminf(vmin[rt][r], c[r]);
            }
            B0 = N0; B1 = N1; B2 = N2; ecv = ecn;
        }
    }

    // reduce mins across the 16-lane group that shares each row; add margin
    float thr[4][4];
#pragma unroll
    for (int rt = 0; rt < 4; ++rt)
#pragma unroll
        for (int r = 0; r < 4; ++r) {
            float v = vmin[rt][r];
#pragma unroll
            for (int m = 1; m < 16; m <<= 1) v = fminf(v, __shfl_xor(v, m));
            thr[rt][r] = v + MARGIN;
        }

    // ---- phase B: re-scan (deterministic recompute), capture candidates ----
    {
        bf16x8 B0 = *(const bf16x8*)(bbase);
        bf16x8 B1 = *(const bf16x8*)(bbase + 32);
        bf16x8 B2 = *(const bf16x8*)(bbase + 64);
        float ecv = ec[l15];
        for (int t = 0; t < NE / 16; ++t) {
            bf16x8 N0 = B0, N1 = B1, N2 = B2;
            float ecn = ecv;
            if (t + 1 < NE / 16) {
                const short* np = bbase + (t + 1) * 16 * KP;
                N0 = *(const bf16x8*)(np);
                N1 = *(const bf16x8*)(np + 32);
                N2 = *(const bf16x8*)(np + 64);
                ecn = ec[(t + 1) * 16 + l15];
            }
            int j0 = t * 16;
#pragma unroll
            for (int rt = 0; rt < 4; ++rt) {
                f32x4 c = {ecv, ecv, ecv, ecv};
                c = __builtin_amdgcn_mfma_f32_16x16x32_bf16(A[rt][0], B0, c, 0, 0, 0);
                c = __builtin_amdgcn_mfma_f32_16x16x32_bf16(A[rt][1], B1, c, 0, 0, 0);
                c = __builtin_amdgcn_mfma_f32_16x16x32_bf16(A[rt][2], B2, c, 0, 0, 0);
#pragma unroll
                for (int r = 0; r < 4; ++r) {
                    if (c[r] <= thr[rt][r]) {   // C layout: col=l15, row=lg*4+r
                        int row = row0 + rt * 16 + lg * 4 + r;
                        int o = atomicAdd(cnt + row, 1);
                        if (o < CAP)
                            list[(size_t)row * CAP + o] = (unsigned short)(j0 + l15);
                    }
                }
            }
            B0 = N0; B1 = N1; B2 = N2; ecv = ecn;
        }
    }
}

// ---------------- exact pass: bit-exact ref score on candidates only --------
__global__ __launch_bounds__(256)
__attribute__((amdgpu_waves_per_eu(1, 2)))
void vq_exact(const float* __restrict__ x,
              const float* __restrict__ en,
              const float* __restrict__ ec,
              const int* __restrict__ cnt,
              const unsigned short* __restrict__ list,
              int* __restrict__ bidx, int n) {
    int row = blockIdx.x * 256 + threadIdx.x;
    if (row >= n) return;
    float X[D];
    const float4* x4 = (const float4*)(x + (size_t)row * D);
#pragma unroll
    for (int i = 0; i < D / 4; ++i) {
        float4 v = x4[i];
        X[4 * i + 0] = v.x; X[4 * i + 1] = v.y;
        X[4 * i + 2] = v.z; X[4 * i + 3] = v.w;
    }
    // A = ||x||^2, numpy pairwise 8-accumulator pattern
    float pr[8];
#pragma unroll
    for (int t = 0; t < 8; ++t) pr[t] = __fmul_rn(X[t], X[t]);
#pragma unroll
    for (int base = 8; base < D; base += 8)
#pragma unroll
        for (int t = 0; t < 8; ++t)
            pr[t] = __fadd_rn(pr[t], __fmul_rn(X[base + t], X[base + t]));
    float A = __fadd_rn(
        __fadd_rn(__fadd_rn(pr[0], pr[1]), __fadd_rn(pr[2], pr[3])),
        __fadd_rn(__fadd_rn(pr[4], pr[5]), __fadd_rn(pr[6], pr[7])));

    float best = 3.4e38f;
    int bi = -1;
    int c = cnt[row];
    if (c > 0 && c <= CAP) {
        for (int i = 0; i < c; ++i) {
            int j = list[(size_t)row * CAP + i];
            const float* ej = en + j * D;
            float d = 0.f;
#pragma unroll
            for (int k = 0; k < D; ++k) d = __builtin_fmaf(X[k], ej[k], d);
            float s = __fadd_rn(__fsub_rn(A, __fmul_rn(2.0f, d)), ec[j]);
            // unordered list: strict < plus lowest-j on exact tie == first-index rule
            if (s < best || (s == best && j < bi)) { best = s; bi = j; }
        }
    } else {  // overflow / empty (never expected): exact full scan
        for (int j = 0; j < NE; ++j) {
            const float* ej = en + j * D;
            float d = 0.f;
#pragma unroll
            for (int k = 0; k < D; ++k) d = __builtin_fmaf(X[k], ej[k], d);
            float s = __fadd_rn(__fsub_rn(A, __fmul_rn(2.0f, d)), ec[j]);
            if (s < best) { best = s; bi = j; }
        }
    }
    bidx[row] = bi;
}

// ---------------- epilogue: coalesced gather/write + loss (proven r3) -------
__global__ __launch_bounds__(256) void vq_epi(
        const float* __restrict__ x,
        const float* __restrict__ w,
        const int* __restrict__ bidx,
        float* __restrict__ out,
        double* __restrict__ loss_acc, int n) {
    const int row0 = blockIdx.x * 64;
    double ss = 0.0;
    for (int f = threadIdx.x; f < 64 * (D / 4); f += 256) {
        int row = f / (D / 4);
        int gr  = row0 + row;
        if (gr < n) {
            int k4  = (f % (D / 4)) * 4;
            int gbi = bidx[gr];
            float4 q  = *(const float4*)(w + gbi * D + k4);
            float4 xv = *(const float4*)(x + (size_t)gr * D + k4);
            float d0 = __fsub_rn(q.x, xv.x), d1 = __fsub_rn(q.y, xv.y);
            float d2 = __fsub_rn(q.z, xv.z), d3 = __fsub_rn(q.w, xv.w);
            float4 o;
            o.x = __fadd_rn(xv.x, d0); o.y = __fadd_rn(xv.y, d1);
            o.z = __fadd_rn(xv.z, d2); o.w = __fadd_rn(xv.w, d3);
            *(float4*)(out + (size_t)gr * D + k4) = o;
            ss += (double)__fmul_rn(d0, d0) + (double)__fmul_rn(d1, d1);
            ss += (double)__fmul_rn(d2, d2) + (double)__fmul_rn(d3, d3);
        }
    }
#pragma unroll
    for (int off = 32; off > 0; off >>= 1) ss += __shfl_down(ss, off);
    __shared__ double bsum[4];
    int wid = threadIdx.x >> 6;
    if ((threadIdx.x & 63) == 0) bsum[wid] = ss;
    __syncthreads();
    if (threadIdx.x == 0)
        atomicAdd(loss_acc, bsum[0] + bsum[1] + bsum[2] + bsum[3]);
}

__global__ void vq_fin_kernel(const double* __restrict__ acc,
                              float* __restrict__ out_loss,
                              double count) {
    float m = (float)(*acc / count);
    *out_loss = __fadd_rn(m, __fmul_rn(0.25f, m));
}

// ---------------- fallback (ws too small): round-2 exact path ---------------
__global__ __launch_bounds__(64)
__attribute__((amdgpu_waves_per_eu(2, 2)))
void vq_main_exact(const float* __restrict__ x, const float* __restrict__ w,
                   const float* __restrict__ en, const float* __restrict__ ec,
                   float* __restrict__ out, double* __restrict__ loss_acc, int n) {
    const int r = blockIdx.x * 64 + threadIdx.x;
    double ss = 0.0;
    if (r < n) {
        float X[D];
        const float4* x4 = (const float4*)(x + (size_t)r * D);
#pragma unroll
        for (int i = 0; i < D / 4; ++i) {
            float4 v = x4[i];
            X[4 * i + 0] = v.x; X[4 * i + 1] = v.y;
            X[4 * i + 2] = v.z; X[4 * i + 3] = v.w;
        }
        float pr[8];
#pragma unroll
        for (int t = 0; t < 8; ++t) pr[t] = __fmul_rn(X[t], X[t]);
#pragma unroll
        for (int base = 8; base < D; base += 8)
#pragma unroll
            for (int t = 0; t < 8; ++t)
                pr[t] = __fadd_rn(pr[t], __fmul_rn(X[base + t], X[base + t]));
        float A = __fadd_rn(
            __fadd_rn(__fadd_rn(pr[0], pr[1]), __fadd_rn(pr[2], pr[3])),
            __fadd_rn(__fadd_rn(pr[4], pr[5]), __fadd_rn(pr[6], pr[7])));
        float best = 3.4e38f; int bi = 0;
        for (int j = 0; j < NE; ++j) {
            const float* ej = en + j * D;
            float d = 0.f;
#pragma unroll
            for (int k = 0; k < D; ++k) d = __builtin_fmaf(X[k], ej[k], d);
            float s = __fadd_rn(__fsub_rn(A, __fmul_rn(2.0f, d)), ec[j]);
            if (s < best) { best = s; bi = j; }
        }
        const float* wj = w + bi * D;
        float4* o4 = (float4*)(out + (size_t)r * D);
#pragma unroll
        for (int i = 0; i < D / 4; ++i) {
            float q0 = wj[4*i+0], q1 = wj[4*i+1], q2 = wj[4*i+2], q3 = wj[4*i+3];
            float d0 = __fsub_rn(q0, X[4*i+0]), d1 = __fsub_rn(q1, X[4*i+1]);
            float d2 = __fsub_rn(q2, X[4*i+2]), d3 = __fsub_rn(q3, X[4*i+3]);
            float4 o;
            o.x = __fadd_rn(X[4*i+0], d0); o.y = __fadd_rn(X[4*i+1], d1);
            o.z = __fadd_rn(X[4*i+2], d2); o.w = __fadd_rn(X[4*i+3], d3);
            o4[i] = o;
            ss += (double)__fmul_rn(d0, d0) + (double)__fmul_rn(d1, d1);
            ss += (double)__fmul_rn(d2, d2) + (double)__fmul_rn(d3, d3);
        }
    }
#pragma unroll
    for (int off = 32; off > 0; off >>= 1) ss += __shfl_down(ss, off);
    if (threadIdx.x == 0) atomicAdd(loss_acc, ss);
}

extern "C" void kernel_launch(void* const* d_in, const int* in_sizes, int n_in,
                              void* d_out, int out_size, void* d_ws, size_t ws_size,
                              hipStream_t stream) {
    const float* x = (const float*)d_in[0];   // cnt_emb [64,2048,80]
    const float* w = (const float*)d_in[1];   // embed_weight [1024,80]
    float* out = (float*)d_out;
    int n = in_sizes[0] / D;                  // 131072 rows

    char* ws = (char*)d_ws;
    double* acc = (double*)(ws + OFF_ACC);
    float*  en  = (float*)(ws + OFF_EN);
    float*  ec  = (float*)(ws + OFF_EC);

    hipMemsetAsync(ws + OFF_ACC, 0, 64, stream);
    if (ws_size >= WS_NEED) {
        short* enb = (short*)(ws + OFF_ENB);
        int*   bidx = (int*)(ws + OFF_BIDX);
        int*   cnt  = (int*)(ws + OFF_CNT);
        unsigned short* list = (unsigned short*)(ws + OFF_LIST);
        hipMemsetAsync(cnt, 0, (size_t)n * 4, stream);
        vq_prep<<<(NE + 255) / 256, 256, 0, stream>>>(w, en, ec, enb);
        vq_mfma<<<n / 256, 256, 0, stream>>>(x, enb, ec, cnt, list, n);
        vq_exact<<<n / 256, 256, 0, stream>>>(x, en, ec, cnt, list, bidx, n);
        vq_epi<<<n / 64, 256, 0, stream>>>(x, w, bidx, out, acc, n);
    } else {
        short* enb_dummy = (short*)(ws + OFF_EC + 4096);  // unused path scratch
        vq_prep<<<(NE + 255) / 256, 256, 0, stream>>>(w, en, ec, enb_dummy);
        vq_main_exact<<<(n + 63) / 64, 64, 0, stream>>>(x, w, en, ec, out, acc, n);
    }
    vq_fin_kernel<<<1, 1, 0, stream>>>(acc, out + (size_t)n * D, (double)n * D);
}